// Round 3
// baseline (7944.791 us; speedup 1.0000x reference)
//
#include <hip/hip_runtime.h>
#include <hip/hip_fp16.h>
#include <stdint.h>

typedef _Float16 h8 __attribute__((ext_vector_type(8)));
typedef float f4 __attribute__((ext_vector_type(4)));

#define MFMA16(a, b, c) __builtin_amdgcn_mfma_f32_16x16x32_f16((a), (b), (c), 0, 0, 0)

#define RSLOT 16
#define FSTR 260
// each flag on its own 64B line
#define FIDX(l, t) ((((l) * FSTR) + (t)) << 4)

constexpr size_t HBUF_OFF = 0;
constexpr size_t HBUF_BYTES = 10ull * RSLOT * 64 * 64 * 8 * 2;   // 10,485,760
constexpr size_t X_OFF = HBUF_OFF + HBUF_BYTES;
constexpr size_t X_BYTES = 256ull * 4096 * 2;                    // 2,097,152
constexpr size_t STRM_OFF = X_OFF + X_BYTES;
constexpr size_t STRM_BYTES = 234ull * 15360;                    // 3,594,240
constexpr size_t RDY_OFF = STRM_OFF + STRM_BYTES;
constexpr size_t RDY_BYTES = 10ull * FSTR * 16 * 4;              // 166,400
constexpr size_t DONE_OFF = RDY_OFF + RDY_BYTES;
constexpr size_t WS_NEED = DONE_OFF + RDY_BYTES;

__device__ __forceinline__ void spin_ge(int* p, int tgt) {
  int it = 0;
  while (__hip_atomic_load(p, __ATOMIC_RELAXED, __HIP_MEMORY_SCOPE_AGENT) < tgt) {
    __builtin_amdgcn_s_sleep(1);
    if (++it > 200000) break;   // bail: wrong answer beats a hang
  }
}

// device-coherent 16B load as two 8B relaxed agent atomics (sc1, no fence)
__device__ __forceinline__ h8 ld_h8_dc(const __half* p) {
  const unsigned long long* q = (const unsigned long long*)p;
  unsigned long long lo = __hip_atomic_load(q,     __ATOMIC_RELAXED, __HIP_MEMORY_SCOPE_AGENT);
  unsigned long long hi = __hip_atomic_load(q + 1, __ATOMIC_RELAXED, __HIP_MEMORY_SCOPE_AGENT);
  union { unsigned long long u[2]; h8 v; } r;
  r.u[0] = lo; r.u[1] = hi;
  return r.v;
}

// device-coherent 2B store (write-through to coherence point)
__device__ __forceinline__ void st_h_dc(__half* p, float x) {
  __hip_atomic_store((unsigned short*)p, __half_as_ushort(__float2half(x)),
                     __ATOMIC_RELAXED, __HIP_MEMORY_SCOPE_AGENT);
}

__device__ __forceinline__ int colrow_main(int c, int S, int hbase) {
  int g, hl;
  if (c < 64) { g = c >> 4; hl = c & 15; }
  else { int j = c - 64; g = j & 3; hl = 16 + (j >> 2); }
  if (hl >= S) hl = S - 1;
  return g * 512 + hbase + hl;
}

__device__ __forceinline__ float sigm(float x) {
  return __fdividef(1.f, 1.f + __expf(-x));
}
__device__ __forceinline__ float tanh_f(float x) {
  return 1.f - __fdividef(2.f, __expf(2.f * x) + 1.f);
}

// ---------------- prep kernels ----------------

__global__ __launch_bounds__(256) void zero_kernel(char* ws) {
  int i = blockIdx.x * 256 + threadIdx.x;
  if (i < 163840) {                        // slot 0 of each layer's h ring
    int layer = i >> 14;
    int w = i & 16383;
    ((int*)(ws + HBUF_OFF))[(size_t)layer * RSLOT * 16384 + w] = 0;
  } else {
    int j = i - 163840;
    if (j < 2 * 10 * FSTR * 16) ((int*)(ws + RDY_OFF))[j] = 0;
  }
}

__global__ __launch_bounds__(256) void xprep_kernel(const float* __restrict__ X, char* ws) {
  int u = blockIdx.x * 256 + threadIdx.x;
  if (u >= 131072) return;
  int t = u >> 9, rem = u & 511, kg = rem >> 6, b = rem & 63;
  const float* src = X + ((size_t)b * 256 + t) * 64 + kg * 8;
  h8 v;
#pragma unroll
  for (int j = 0; j < 8; ++j) v[j] = (_Float16)src[j];
  *(h8*)(ws + X_OFF + (size_t)u * 16) = v;
}

__global__ __launch_bounds__(256) void wsprep_kernel(const float* __restrict__ Whh, char* ws) {
  int u = blockIdx.x * 256 + threadIdx.x;
  if (u >= 234 * 15 * 64) return;
  int cu = u / 960, rem = u % 960;
  int f = rem >> 6, l = rem & 63;
  int ktm = f / 5, nt = f % 5, kt = 29 + ktm;
  int L = 1 + cu / 26, cl = cu % 26;
  int S = cl < 18 ? 20 : 19;
  int hbase = cl < 18 ? 20 * cl : 360 + 19 * (cl - 18);
  int c = 16 * nt + (l & 15);
  int row = colrow_main(c, S, hbase);
  int k = kt * 32 + (l >> 4) * 8;
  const float* src = Whh + ((size_t)L * 2048 + row) * 512 + (k - 512);
  h8 v;
#pragma unroll
  for (int j = 0; j < 8; ++j) v[j] = (_Float16)src[j];
  *(h8*)(ws + STRM_OFF + (size_t)cu * 15360 + (size_t)f * 1024 + (size_t)l * 16) = v;
}

// ---------------- main persistent kernel ----------------

__global__ __launch_bounds__(256, 1) void lstm_fused(
    const float* __restrict__ X, const float* __restrict__ Wih0,
    const float* __restrict__ Wih, const float* __restrict__ Whh,
    const float* __restrict__ bih, const float* __restrict__ bhh,
    const float* __restrict__ Wout, const float* __restrict__ bout,
    float* __restrict__ out, char* __restrict__ ws)
{
  extern __shared__ char lds[];
  const int blk = blockIdx.x;
  const int role = (blk & 7) * 32 + (blk >> 3);

  __half* hbuf = (__half*)(ws + HBUF_OFF);
  const __half* xt = (const __half*)(ws + X_OFF);
  int* rdy = (int*)(ws + RDY_OFF);
  int* dn  = (int*)(ws + DONE_OFF);

  const int tid = threadIdx.x;
  const int lane = tid & 63;
  const int wv = tid >> 6;
  const int pp = lane & 15;
  const int lg = lane >> 4;
  const int n = wv & 1, m = wv >> 1;
  const int ab0 = lg * 512 + (16 * (2 * m) + pp) * 8;
  const int ab1 = ab0 + 128;

  if (role >= 250) {
    // ================= head on 6 spare CUs =================
    const int hd = role - 250;
    const int d0 = hd * 11;
    const int nd = (hd < 5) ? 11 : 9;
    const int b = lane;
    const float* wrow0 = Wout + (size_t)(d0 + wv + 0) * 512;
    const float* wrow1 = Wout + (size_t)(d0 + wv + 4) * 512;
    const float* wrow2 = Wout + (size_t)(d0 + wv + 8) * 512;
    const bool a0ok = (wv + 0) < nd;
    const bool a1ok = (wv + 4) < nd;
    const bool a2ok = (wv + 8) < nd;
    for (int th = 0; th < 256; ++th) {
      if (tid == 0) spin_ge(rdy + FIDX(9, th), 26);
      __syncthreads();
      const __half* h9 = hbuf + ((size_t)9 * RSLOT + ((th + 1) & 15)) * 32768;
      float a0 = a0ok ? bout[d0 + wv + 0] : 0.f;
      float a1 = a1ok ? bout[d0 + wv + 4] : 0.f;
      float a2 = a2ok ? bout[d0 + wv + 8] : 0.f;
#pragma unroll 8
      for (int kg = 0; kg < 64; ++kg) {
        h8 hv = ld_h8_dc(h9 + (size_t)kg * 512 + b * 8);
        float hf[8];
#pragma unroll
        for (int j = 0; j < 8; ++j) hf[j] = (float)hv[j];
        if (a0ok) {
          f4 w0 = *(const f4*)(wrow0 + kg * 8);
          f4 w1 = *(const f4*)(wrow0 + kg * 8 + 4);
          a0 += hf[0]*w0[0] + hf[1]*w0[1] + hf[2]*w0[2] + hf[3]*w0[3]
              + hf[4]*w1[0] + hf[5]*w1[1] + hf[6]*w1[2] + hf[7]*w1[3];
        }
        if (a1ok) {
          f4 w0 = *(const f4*)(wrow1 + kg * 8);
          f4 w1 = *(const f4*)(wrow1 + kg * 8 + 4);
          a1 += hf[0]*w0[0] + hf[1]*w0[1] + hf[2]*w0[2] + hf[3]*w0[3]
              + hf[4]*w1[0] + hf[5]*w1[1] + hf[6]*w1[2] + hf[7]*w1[3];
        }
        if (a2ok) {
          f4 w0 = *(const f4*)(wrow2 + kg * 8);
          f4 w1 = *(const f4*)(wrow2 + kg * 8 + 4);
          a2 += hf[0]*w0[0] + hf[1]*w0[1] + hf[2]*w0[2] + hf[3]*w0[3]
              + hf[4]*w1[0] + hf[5]*w1[1] + hf[6]*w1[2] + hf[7]*w1[3];
        }
      }
      if (a0ok) out[(size_t)b * 16384 + (size_t)th * 64 + d0 + wv + 0] = a0;
      if (a1ok) out[(size_t)b * 16384 + (size_t)th * 64 + d0 + wv + 4] = a1;
      if (a2ok) out[(size_t)b * 16384 + (size_t)th * 64 + d0 + wv + 8] = a2;
      __syncthreads();   // reads done before releasing the slot
      if (tid == 0)
        __hip_atomic_fetch_add(dn + FIDX(9, th + 1), 1,
                               __ATOMIC_RELAXED, __HIP_MEMORY_SCOPE_AGENT);
    }
    return;
  }

  if (role < 16) {
    // ================= layer 0 (pure cell) =================
    const int cu = role;
    const int hbase = cu * 32;
    for (int ch = tid; ch < 9216; ch += 256) {
      int c = ch / 72, kc = (ch % 72) * 8;
      int g = (c >> 4) & 3;
      int hl = ((c >> 6) << 4) + (c & 15);
      int row = g * 512 + hbase + hl;
      const float* src = (kc < 64) ? (Wih0 + (size_t)row * 64 + kc)
                                   : (Whh + (size_t)row * 512 + (kc - 64));
      h8 v;
#pragma unroll
      for (int j = 0; j < 8; ++j) v[j] = (_Float16)src[j];
      uint32_t off = ((uint32_t)(c * 1152 + kc * 2)) ^ (uint32_t)((c & 7) << 4);
      *(h8*)(lds + off) = v;
    }
    float bias0[4];
#pragma unroll
    for (int j = 0; j < 4; ++j) {
      int row = j * 512 + hbase + n * 16 + pp;
      bias0[j] = bih[row] + bhh[row];
    }
    __syncthreads();

    float cv[2][4] = {{0.f,0.f,0.f,0.f},{0.f,0.f,0.f,0.f}};

    for (int t = 0; t < 256; ++t) {
      if (tid == 0) {
        if (t > 0) spin_ge(rdy + FIDX(0, t - 1), 16);
        if (t >= 15) spin_ge(dn + FIDX(0, t - 15), (t == 15) ? 16 : 42);
      }
      __syncthreads();

      const __half* Ax = xt + (size_t)t * 4096;
      const __half* As = hbuf + (size_t)(t & 15) * 32768;
      f4 acc[2][4];
#pragma unroll
      for (int mi = 0; mi < 2; ++mi)
#pragma unroll
        for (int j = 0; j < 4; ++j) acc[mi][j] = (f4){0.f, 0.f, 0.f, 0.f};

#pragma unroll
      for (int kt = 0; kt < 2; ++kt) {
        h8 a0 = *(const h8*)(Ax + kt * 2048 + ab0);
        h8 a1 = *(const h8*)(Ax + kt * 2048 + ab1);
#pragma unroll
        for (int j = 0; j < 4; ++j) {
          int c = 16 * (4 * n + j) + pp;
          uint32_t off = ((uint32_t)(c * 1152 + kt * 64 + lg * 16)) ^ (uint32_t)((c & 7) << 4);
          h8 bv = *(const h8*)(lds + off);
          acc[0][j] = MFMA16(a0, bv, acc[0][j]);
          acc[1][j] = MFMA16(a1, bv, acc[1][j]);
        }
      }
#pragma unroll 8
      for (int kt = 2; kt < 18; ++kt) {
        h8 a0 = ld_h8_dc(As + (kt - 2) * 2048 + ab0);
        h8 a1 = ld_h8_dc(As + (kt - 2) * 2048 + ab1);
#pragma unroll
        for (int j = 0; j < 4; ++j) {
          int c = 16 * (4 * n + j) + pp;
          uint32_t off = ((uint32_t)(c * 1152 + kt * 64 + lg * 16)) ^ (uint32_t)((c & 7) << 4);
          h8 bv = *(const h8*)(lds + off);
          acc[0][j] = MFMA16(a0, bv, acc[0][j]);
          acc[1][j] = MFMA16(a1, bv, acc[1][j]);
        }
      }
      __half* Hd = hbuf + (size_t)((t + 1) & 15) * 32768;
      const int hg = hbase + n * 16 + pp;
#pragma unroll
      for (int mi = 0; mi < 2; ++mi) {
        int bbb = 16 * (2 * m + mi) + 4 * lg;
#pragma unroll
        for (int r = 0; r < 4; ++r) {
          float gi = sigm(acc[mi][0][r] + bias0[0]);
          float gf = sigm(acc[mi][1][r] + bias0[1]);
          float gg = tanh_f(acc[mi][2][r] + bias0[2]);
          float go = sigm(acc[mi][3][r] + bias0[3]);
          float c2 = gf * cv[mi][r] + gi * gg;
          cv[mi][r] = c2;
          st_h_dc(Hd + (size_t)(hg >> 3) * 512 + (bbb + r) * 8 + (hg & 7),
                  go * tanh_f(c2));
        }
      }
      __syncthreads();   // drains vmcnt: sc1 stores acked before flag add
      if (tid == 0) {
        __hip_atomic_fetch_add(rdy + FIDX(0, t), 1, __ATOMIC_RELAXED, __HIP_MEMORY_SCOPE_AGENT);
        __hip_atomic_fetch_add(dn  + FIDX(0, t), 1, __ATOMIC_RELAXED, __HIP_MEMORY_SCOPE_AGENT);
      }
    }
    return;
  }

  // ================= layers 1..9 =================
  const int cuIdx = role - 16;
  const int L = 1 + cuIdx / 26;
  const int cl = cuIdx % 26;
  const int S = cl < 18 ? 20 : 19;
  const int hbase = cl < 18 ? 20 * cl : 360 + 19 * (cl - 18);
  const float* WihL = Wih + (size_t)(L - 1) * 1048576;
  const float* WhhL = Whh + (size_t)L * 1048576;
  const float* bihL = bih + L * 2048;
  const float* bhhL = bhh + L * 2048;

  for (int ch = tid; ch < 9280; ch += 256) {
    int c = ch / 116, kc = (ch % 116) * 8;
    int row = colrow_main(c, S, hbase);
    const float* src = (kc < 512) ? (WihL + (size_t)row * 512 + kc)
                                  : (WhhL + (size_t)row * 512 + (kc - 512));
    h8 v;
#pragma unroll
    for (int j = 0; j < 8; ++j) v[j] = (_Float16)src[j];
    uint32_t off = ((uint32_t)(c * 1856 + kc * 2)) ^ (uint32_t)((c & 7) << 4);
    *(h8*)(lds + off) = v;
  }
  float biasv[4], bsp[4];
#pragma unroll
  for (int j = 0; j < 4; ++j) {
    int row = colrow_main(16 * j + pp, S, hbase);
    biasv[j] = bihL[row] + bhhL[row];
    int rs = colrow_main(64 + 4 * (pp >> 2) + j, S, hbase);
    bsp[j] = bihL[rs] + bhhL[rs];
  }
  __syncthreads();

  const int ncuP = (L == 1) ? 16 : 26;
  const int dnTgt = (L == 9) ? 32 : 52;
  const int ntA = n ? 3 : 0;
  const int cA = 16 * ntA + pp, cB = cA + 16, c2c = 32 + pp;
  const char* strm = ws + STRM_OFF + (size_t)cuIdx * 15360;
  float* xch = (float*)(lds + 148480);

  float cv[2][2] = {{0.f,0.f},{0.f,0.f}};
  float csp[2][2] = {{0.f,0.f},{0.f,0.f}};

  for (int t = 0; t < 256; ++t) {
    if (tid == 0) {
      spin_ge(rdy + FIDX(L - 1, t), ncuP);
      if (t > 0) spin_ge(rdy + FIDX(L, t - 1), 26);
      if (t >= 15) spin_ge(dn + FIDX(L, t - 15), (t == 15) ? 26 : dnTgt);
    }
    __syncthreads();

    const __half* Abot = hbuf + ((size_t)(L - 1) * RSLOT + ((t + 1) & 15)) * 32768;
    const __half* Asel = hbuf + ((size_t)L * RSLOT + (t & 15)) * 32768;

    f4 acc[2][3];
#pragma unroll
    for (int mi = 0; mi < 2; ++mi)
#pragma unroll
      for (int j = 0; j < 3; ++j) acc[mi][j] = (f4){0.f, 0.f, 0.f, 0.f};

#pragma unroll 8
    for (int kt = 0; kt < 16; ++kt) {
      h8 a0 = ld_h8_dc(Abot + kt * 2048 + ab0);
      h8 a1 = ld_h8_dc(Abot + kt * 2048 + ab1);
      uint32_t o0 = ((uint32_t)(cA * 1856 + kt * 64 + lg * 16)) ^ (uint32_t)((cA & 7) << 4);
      uint32_t o1 = ((uint32_t)(cB * 1856 + kt * 64 + lg * 16)) ^ (uint32_t)((cB & 7) << 4);
      h8 b0 = *(const h8*)(lds + o0);
      h8 b1 = *(const h8*)(lds + o1);
      acc[0][0] = MFMA16(a0, b0, acc[0][0]);
      acc[1][0] = MFMA16(a1, b0, acc[1][0]);
      acc[0][1] = MFMA16(a0, b1, acc[0][1]);
      acc[1][1] = MFMA16(a1, b1, acc[1][1]);
      if (n == 0) {
        uint32_t o2 = ((uint32_t)(c2c * 1856 + kt * 64 + lg * 16)) ^ (uint32_t)((c2c & 7) << 4);
        h8 b2 = *(const h8*)(lds + o2);
        acc[0][2] = MFMA16(a0, b2, acc[0][2]);
        acc[1][2] = MFMA16(a1, b2, acc[1][2]);
      }
    }
#pragma unroll 8
    for (int kt = 16; kt < 29; ++kt) {
      h8 a0 = ld_h8_dc(Asel + (kt - 16) * 2048 + ab0);
      h8 a1 = ld_h8_dc(Asel + (kt - 16) * 2048 + ab1);
      uint32_t o0 = ((uint32_t)(cA * 1856 + kt * 64 + lg * 16)) ^ (uint32_t)((cA & 7) << 4);
      uint32_t o1 = ((uint32_t)(cB * 1856 + kt * 64 + lg * 16)) ^ (uint32_t)((cB & 7) << 4);
      h8 b0 = *(const h8*)(lds + o0);
      h8 b1 = *(const h8*)(lds + o1);
      acc[0][0] = MFMA16(a0, b0, acc[0][0]);
      acc[1][0] = MFMA16(a1, b0, acc[1][0]);
      acc[0][1] = MFMA16(a0, b1, acc[0][1]);
      acc[1][1] = MFMA16(a1, b1, acc[1][1]);
      if (n == 1) {
        uint32_t o2 = ((uint32_t)(c2c * 1856 + kt * 64 + lg * 16)) ^ (uint32_t)((c2c & 7) << 4);
        h8 b2 = *(const h8*)(lds + o2);
        acc[0][2] = MFMA16(a0, b2, acc[0][2]);
        acc[1][2] = MFMA16(a1, b2, acc[1][2]);
      }
    }
#pragma unroll
    for (int kt = 29; kt < 32; ++kt) {
      h8 a0 = ld_h8_dc(Asel + (kt - 16) * 2048 + ab0);
      h8 a1 = ld_h8_dc(Asel + (kt - 16) * 2048 + ab1);
      h8 b0 = *(const h8*)(strm + ((kt - 29) * 5 + ntA) * 1024 + lane * 16);
      h8 b1 = *(const h8*)(strm + ((kt - 29) * 5 + ntA + 1) * 1024 + lane * 16);
      acc[0][0] = MFMA16(a0, b0, acc[0][0]);
      acc[1][0] = MFMA16(a1, b0, acc[1][0]);
      acc[0][1] = MFMA16(a0, b1, acc[0][1]);
      acc[1][1] = MFMA16(a1, b1, acc[1][1]);
      if (n == 1) {
        h8 b2 = *(const h8*)(strm + ((kt - 29) * 5 + 2) * 1024 + lane * 16);
        acc[0][2] = MFMA16(a0, b2, acc[0][2]);
        acc[1][2] = MFMA16(a1, b2, acc[1][2]);
      }
    }

    {
      int idx = 0;
#pragma unroll
      for (int mi = 0; mi < 2; ++mi)
#pragma unroll
        for (int ntl = 0; ntl < 3; ++ntl)
#pragma unroll
          for (int rj = 0; rj < 2; ++rj) {
            float sv = (n == 0) ? acc[mi][ntl][2 + rj] : acc[mi][ntl][rj];
            xch[(wv * 12 + idx) * 64 + lane] = sv;
            ++idx;
          }
    }
    __syncthreads();
    float F[2][5][2];
    {
      const int pw = wv ^ 1;
#pragma unroll
      for (int mi = 0; mi < 2; ++mi)
#pragma unroll
        for (int rj = 0; rj < 2; ++rj) {
          float r0 = xch[(pw * 12 + (mi * 3 + 0) * 2 + rj) * 64 + lane];
          float r1 = xch[(pw * 12 + (mi * 3 + 1) * 2 + rj) * 64 + lane];
          float r2 = xch[(pw * 12 + (mi * 3 + 2) * 2 + rj) * 64 + lane];
          float o0, o1, o2;
          if (n == 0) { o0 = acc[mi][0][rj]; o1 = acc[mi][1][rj]; o2 = acc[mi][2][rj]; }
          else        { o0 = acc[mi][0][2 + rj]; o1 = acc[mi][1][2 + rj]; o2 = acc[mi][2][2 + rj]; }
          if (n == 0) {
            F[mi][0][rj] = o0; F[mi][1][rj] = o1; F[mi][2][rj] = o2 + r2;
            F[mi][3][rj] = r0; F[mi][4][rj] = r1;
          } else {
            F[mi][0][rj] = r0; F[mi][1][rj] = r1; F[mi][2][rj] = o2 + r2;
            F[mi][3][rj] = o0; F[mi][4][rj] = o1;
          }
        }
    }

    __half* Hd = hbuf + ((size_t)L * RSLOT + ((t + 1) & 15)) * 32768;
    const int rrb = n ? 2 : 0;
    const int pm = lane & 3;
#pragma unroll
    for (int mi = 0; mi < 2; ++mi) {
#pragma unroll
      for (int rj = 0; rj < 2; ++rj) {
        int bbb = 16 * (2 * m + mi) + 4 * lg + rrb + rj;
        float gi = sigm(F[mi][0][rj] + biasv[0]);
        float gf = sigm(F[mi][1][rj] + biasv[1]);
        float gg = tanh_f(F[mi][2][rj] + biasv[2]);
        float go = sigm(F[mi][3][rj] + biasv[3]);
        float cc = gf * cv[mi][rj] + gi * gg;
        cv[mi][rj] = cc;
        {
          int hg = hbase + pp;
          st_h_dc(Hd + (size_t)(hg >> 3) * 512 + bbb * 8 + (hg & 7),
                  go * tanh_f(cc));
        }
        float va = F[mi][4][rj];
        float vb = __shfl_xor(va, 1);
        float vc = __shfl_xor(va, 2);
        float vd = __shfl_xor(vb, 2);
        float q0 = (pm & 2) ? ((pm & 1) ? vd : vc) : ((pm & 1) ? vb : va);
        float q1 = (pm & 2) ? ((pm & 1) ? vc : vd) : ((pm & 1) ? va : vb);
        float q2 = (pm & 2) ? ((pm & 1) ? vb : va) : ((pm & 1) ? vd : vc);
        float q3 = (pm & 2) ? ((pm & 1) ? va : vb) : ((pm & 1) ? vc : vd);
        float si = sigm(q0 + bsp[0]);
        float sf = sigm(q1 + bsp[1]);
        float sg = tanh_f(q2 + bsp[2]);
        float so = sigm(q3 + bsp[3]);
        float c3 = sf * csp[mi][rj] + si * sg;
        csp[mi][rj] = c3;
        float hs = so * tanh_f(c3);
        int hj = 16 + (pp >> 2);
        if (pm == 0 && hj < S) {
          int hg = hbase + hj;
          st_h_dc(Hd + (size_t)(hg >> 3) * 512 + bbb * 8 + (hg & 7), hs);
        }
      }
    }

    __syncthreads();   // drains vmcnt: sc1 stores acked before flag adds
    if (tid == 0) {
      __hip_atomic_fetch_add(rdy + FIDX(L, t), 1, __ATOMIC_RELAXED, __HIP_MEMORY_SCOPE_AGENT);
      __hip_atomic_fetch_add(dn + FIDX(L - 1, t + 1), 1, __ATOMIC_RELAXED, __HIP_MEMORY_SCOPE_AGENT);
      __hip_atomic_fetch_add(dn + FIDX(L, t), 1, __ATOMIC_RELAXED, __HIP_MEMORY_SCOPE_AGENT);
    }
  }
}

// ---------------- host ----------------

extern "C" void kernel_launch(void* const* d_in, const int* in_sizes, int n_in,
                              void* d_out, int out_size, void* d_ws, size_t ws_size,
                              hipStream_t stream) {
  const float* X    = (const float*)d_in[0];
  const float* Wih0 = (const float*)d_in[1];
  const float* Wih  = (const float*)d_in[2];
  const float* Whh  = (const float*)d_in[3];
  const float* bihp = (const float*)d_in[4];
  const float* bhhp = (const float*)d_in[5];
  const float* Wout = (const float*)d_in[6];
  const float* bout = (const float*)d_in[7];
  float* out = (float*)d_out;
  char* ws = (char*)d_ws;
  (void)in_sizes; (void)n_in; (void)out_size;
  if (ws_size < WS_NEED) return;

  hipFuncSetAttribute((const void*)lstm_fused,
                      hipFuncAttributeMaxDynamicSharedMemorySize, 163840);

  zero_kernel<<<966, 256, 0, stream>>>(ws);
  xprep_kernel<<<512, 256, 0, stream>>>(X, ws);
  wsprep_kernel<<<878, 256, 0, stream>>>(Whh, ws);
  lstm_fused<<<256, 256, 163840, stream>>>(X, Wih0, Wih, Whh, bihp, bhhp,
                                           Wout, bout, out, ws);
}

// Round 4
// 6536.245 us; speedup vs baseline: 1.2155x; 1.2155x over previous
//
#include <hip/hip_runtime.h>
#include <hip/hip_fp16.h>
#include <stdint.h>

typedef _Float16 h8 __attribute__((ext_vector_type(8)));
typedef float f4 __attribute__((ext_vector_type(4)));

#define MFMA16(a, b, c) __builtin_amdgcn_mfma_f32_16x16x32_f16((a), (b), (c), 0, 0, 0)

#define RSLOT 16
#define FSTR 260
// each flag on its own 64B line
#define FIDX(l, t) ((((l) * FSTR) + (t)) << 4)

constexpr size_t HBUF_OFF = 0;
constexpr size_t HBUF_BYTES = 10ull * RSLOT * 64 * 64 * 8 * 2;   // 10,485,760
constexpr size_t X_OFF = HBUF_OFF + HBUF_BYTES;
constexpr size_t X_BYTES = 256ull * 4096 * 2;                    // 2,097,152
constexpr size_t STRM_OFF = X_OFF + X_BYTES;
constexpr size_t STRM_BYTES = 234ull * 15360;                    // 3,594,240
constexpr size_t RDY_OFF = STRM_OFF + STRM_BYTES;
constexpr size_t RDY_BYTES = 10ull * FSTR * 16 * 4;              // 166,400
constexpr size_t DONE_OFF = RDY_OFF + RDY_BYTES;
constexpr size_t WS_NEED = DONE_OFF + RDY_BYTES;

__device__ __forceinline__ void spin_ge(int* p, int tgt) {
  int it = 0;
  while (__hip_atomic_load(p, __ATOMIC_RELAXED, __HIP_MEMORY_SCOPE_AGENT) < tgt) {
    __builtin_amdgcn_s_sleep(1);
    if (++it > 200000) break;   // bail: wrong answer beats a hang
  }
}

// L2-bypassing (agent-coherent) 16B load; scheduler-controlled by hand.
// Consumers MUST be preceded by WAITV(N) with correct outstanding count.
__device__ __forceinline__ h8 gld16_sc1(const void* base, int voff) {
  h8 v;
  asm volatile("global_load_dwordx4 %0, %1, %2 sc1"
               : "=v"(v) : "v"(voff), "s"(base));
  return v;
}
// counted wait + scheduling fence (rule: compiler may hoist MFMA past bare waitcnt)
#define WAITV(N) do { asm volatile("s_waitcnt vmcnt(" #N ")" ::: "memory"); \
                      __builtin_amdgcn_sched_barrier(0); } while (0)

// device-coherent 2B store (write-through to coherence point)
__device__ __forceinline__ void st_h_dc(__half* p, float x) {
  __hip_atomic_store((unsigned short*)p, __half_as_ushort(__float2half(x)),
                     __ATOMIC_RELAXED, __HIP_MEMORY_SCOPE_AGENT);
}

__device__ __forceinline__ int colrow_main(int c, int S, int hbase) {
  int g, hl;
  if (c < 64) { g = c >> 4; hl = c & 15; }
  else { int j = c - 64; g = j & 3; hl = 16 + (j >> 2); }
  if (hl >= S) hl = S - 1;
  return g * 512 + hbase + hl;
}

__device__ __forceinline__ float sigm(float x) {
  return __fdividef(1.f, 1.f + __expf(-x));
}
__device__ __forceinline__ float tanh_f(float x) {
  return 1.f - __fdividef(2.f, __expf(2.f * x) + 1.f);
}

// ---------------- prep kernels ----------------

__global__ __launch_bounds__(256) void zero_kernel(char* ws) {
  int i = blockIdx.x * 256 + threadIdx.x;
  if (i < 163840) {                        // slot 0 of each layer's h ring
    int layer = i >> 14;
    int w = i & 16383;
    ((int*)(ws + HBUF_OFF))[(size_t)layer * RSLOT * 16384 + w] = 0;
  } else {
    int j = i - 163840;
    if (j < 2 * 10 * FSTR * 16) ((int*)(ws + RDY_OFF))[j] = 0;
  }
}

__global__ __launch_bounds__(256) void xprep_kernel(const float* __restrict__ X, char* ws) {
  int u = blockIdx.x * 256 + threadIdx.x;
  if (u >= 131072) return;
  int t = u >> 9, rem = u & 511, kg = rem >> 6, b = rem & 63;
  const float* src = X + ((size_t)b * 256 + t) * 64 + kg * 8;
  h8 v;
#pragma unroll
  for (int j = 0; j < 8; ++j) v[j] = (_Float16)src[j];
  *(h8*)(ws + X_OFF + (size_t)u * 16) = v;
}

__global__ __launch_bounds__(256) void wsprep_kernel(const float* __restrict__ Whh, char* ws) {
  int u = blockIdx.x * 256 + threadIdx.x;
  if (u >= 234 * 15 * 64) return;
  int cu = u / 960, rem = u % 960;
  int f = rem >> 6, l = rem & 63;
  int ktm = f / 5, nt = f % 5, kt = 29 + ktm;
  int L = 1 + cu / 26, cl = cu % 26;
  int S = cl < 18 ? 20 : 19;
  int hbase = cl < 18 ? 20 * cl : 360 + 19 * (cl - 18);
  int c = 16 * nt + (l & 15);
  int row = colrow_main(c, S, hbase);
  int k = kt * 32 + (l >> 4) * 8;
  const float* src = Whh + ((size_t)L * 2048 + row) * 512 + (k - 512);
  h8 v;
#pragma unroll
  for (int j = 0; j < 8; ++j) v[j] = (_Float16)src[j];
  *(h8*)(ws + STRM_OFF + (size_t)cu * 15360 + (size_t)f * 1024 + (size_t)l * 16) = v;
}

// ---------------- main persistent kernel ----------------

// K-body for layers 1..9: 5 cols (c = 16j+pp), kt<29 from swizzled LDS weights,
// kt>=29 from LDS-resident streamed fragments.
#define KB(kt, Av) do {                                                        \
  if ((kt) < 29) {                                                             \
    _Pragma("unroll")                                                          \
    for (int j_ = 0; j_ < 5; ++j_) {                                           \
      int c_ = 16 * j_ + pp;                                                   \
      uint32_t off_ = (uint32_t)(c_ * 1856 + (kt) * 64 + lg * 16)              \
                    ^ (uint32_t)((c_ & 7) << 4);                               \
      h8 bv_ = *(const h8*)(lds + off_);                                       \
      acc[j_] = MFMA16((Av), bv_, acc[j_]);                                    \
    }                                                                          \
  } else {                                                                     \
    _Pragma("unroll")                                                          \
    for (int j_ = 0; j_ < 5; ++j_) {                                           \
      h8 bv_ = *(const h8*)(lds + 148480 + (((kt) - 29) * 5 + j_) * 1024       \
                            + lane * 16);                                      \
      acc[j_] = MFMA16((Av), bv_, acc[j_]);                                    \
    }                                                                          \
  }                                                                            \
} while (0)

// K-body for layer 0: 8 cols, stride 1152
#define KB0(kt, Av) do {                                                       \
  _Pragma("unroll")                                                            \
  for (int j_ = 0; j_ < 8; ++j_) {                                             \
    int c_ = 16 * j_ + pp;                                                     \
    uint32_t off_ = (uint32_t)(c_ * 1152 + (kt) * 64 + lg * 16)                \
                  ^ (uint32_t)((c_ & 7) << 4);                                 \
    h8 bv_ = *(const h8*)(lds + off_);                                         \
    acc[j_] = MFMA16((Av), bv_, acc[j_]);                                      \
  }                                                                            \
} while (0)

// head dot-product chunk: 16 kg of h9 against 3 Wout rows
#define KH(kb, H) do {                                                         \
  _Pragma("unroll")                                                            \
  for (int i_ = 0; i_ < 16; ++i_) {                                            \
    int kg_ = (kb) + i_;                                                       \
    h8 hv_ = H[i_];                                                            \
    float hf_[8];                                                              \
    _Pragma("unroll")                                                          \
    for (int j_ = 0; j_ < 8; ++j_) hf_[j_] = (float)hv_[j_];                   \
    if (a0ok) {                                                                \
      f4 w0_ = *(const f4*)(wrow0 + kg_ * 8);                                  \
      f4 w1_ = *(const f4*)(wrow0 + kg_ * 8 + 4);                              \
      a0 += hf_[0]*w0_[0] + hf_[1]*w0_[1] + hf_[2]*w0_[2] + hf_[3]*w0_[3]      \
          + hf_[4]*w1_[0] + hf_[5]*w1_[1] + hf_[6]*w1_[2] + hf_[7]*w1_[3];     \
    }                                                                          \
    if (a1ok) {                                                                \
      f4 w0_ = *(const f4*)(wrow1 + kg_ * 8);                                  \
      f4 w1_ = *(const f4*)(wrow1 + kg_ * 8 + 4);                              \
      a1 += hf_[0]*w0_[0] + hf_[1]*w0_[1] + hf_[2]*w0_[2] + hf_[3]*w0_[3]      \
          + hf_[4]*w1_[0] + hf_[5]*w1_[1] + hf_[6]*w1_[2] + hf_[7]*w1_[3];     \
    }                                                                          \
    if (a2ok) {                                                                \
      f4 w0_ = *(const f4*)(wrow2 + kg_ * 8);                                  \
      f4 w1_ = *(const f4*)(wrow2 + kg_ * 8 + 4);                              \
      a2 += hf_[0]*w0_[0] + hf_[1]*w0_[1] + hf_[2]*w0_[2] + hf_[3]*w0_[3]      \
          + hf_[4]*w1_[0] + hf_[5]*w1_[1] + hf_[6]*w1_[2] + hf_[7]*w1_[3];     \
    }                                                                          \
  }                                                                            \
} while (0)

__global__ __launch_bounds__(256, 1) void lstm_fused(
    const float* __restrict__ X, const float* __restrict__ Wih0,
    const float* __restrict__ Wih, const float* __restrict__ Whh,
    const float* __restrict__ bih, const float* __restrict__ bhh,
    const float* __restrict__ Wout, const float* __restrict__ bout,
    float* __restrict__ out, char* __restrict__ ws)
{
  extern __shared__ char lds[];
  const int blk = blockIdx.x;
  const int role = (blk & 7) * 32 + (blk >> 3);   // XCD-contiguous role mapping

  __half* hbuf = (__half*)(ws + HBUF_OFF);
  const __half* xt = (const __half*)(ws + X_OFF);
  int* rdy = (int*)(ws + RDY_OFF);
  int* dn  = (int*)(ws + DONE_OFF);

  const int tid = threadIdx.x;
  const int lane = tid & 63;
  const int wv = tid >> 6;
  const int pp = lane & 15;
  const int lg = lane >> 4;
  // per-wave A fragment byte offset within a k-tile: wave owns b-rows [16wv,16wv+16)
  const int abb = lg * 1024 + (16 * wv + pp) * 16;

  if (role >= 250) {
    // ================= head on 6 spare CUs =================
    const int hd = role - 250;
    const int d0 = hd * 11;
    const int nd = (hd < 5) ? 11 : 9;
    const int b = lane;
    const float* wrow0 = Wout + (size_t)(d0 + wv + 0) * 512;
    const float* wrow1 = Wout + (size_t)(d0 + wv + 4) * 512;
    const float* wrow2 = Wout + (size_t)(d0 + wv + 8) * 512;
    const bool a0ok = (wv + 0) < nd;
    const bool a1ok = (wv + 4) < nd;
    const bool a2ok = (wv + 8) < nd;
    for (int th = 0; th < 256; ++th) {
      if (tid == 0) spin_ge(rdy + FIDX(9, th), 26);
      __builtin_amdgcn_s_barrier();         // control-only
      const __half* h9 = hbuf + ((size_t)9 * RSLOT + ((th + 1) & 15)) * 32768;
      h8 H0[16], H1[16], H2[16], H3[16];
#pragma unroll
      for (int i = 0; i < 16; ++i) H0[i] = gld16_sc1(h9, i * 1024 + b * 16);
#pragma unroll
      for (int i = 0; i < 16; ++i) H1[i] = gld16_sc1(h9, (16 + i) * 1024 + b * 16);
      float a0 = a0ok ? bout[d0 + wv + 0] : 0.f;
      float a1 = a1ok ? bout[d0 + wv + 4] : 0.f;
      float a2 = a2ok ? bout[d0 + wv + 8] : 0.f;
      WAITV(16);
      KH(0, H0);
#pragma unroll
      for (int i = 0; i < 16; ++i) H2[i] = gld16_sc1(h9, (32 + i) * 1024 + b * 16);
      WAITV(16);
      KH(16, H1);
#pragma unroll
      for (int i = 0; i < 16; ++i) H3[i] = gld16_sc1(h9, (48 + i) * 1024 + b * 16);
      WAITV(16);
      KH(32, H2);
      WAITV(0);
      KH(48, H3);
      if (a0ok) out[(size_t)b * 16384 + (size_t)th * 64 + d0 + wv + 0] = a0;
      if (a1ok) out[(size_t)b * 16384 + (size_t)th * 64 + d0 + wv + 4] = a1;
      if (a2ok) out[(size_t)b * 16384 + (size_t)th * 64 + d0 + wv + 8] = a2;
      __syncthreads();   // reads done before releasing the slot
      if (tid == 0)
        __hip_atomic_fetch_add(dn + FIDX(9, th + 1), 1,
                               __ATOMIC_RELAXED, __HIP_MEMORY_SCOPE_AGENT);
    }
    return;
  }

  if (role < 16) {
    // ================= layer 0 (pure cell) =================
    const int cu = role;
    const int hbase = cu * 32;
    for (int ch = tid; ch < 9216; ch += 256) {
      int c = ch / 72, kc = (ch % 72) * 8;
      int g = (c >> 4) & 3;
      int hl = ((c >> 6) << 4) + (c & 15);
      int row = g * 512 + hbase + hl;
      const float* src = (kc < 64) ? (Wih0 + (size_t)row * 64 + kc)
                                   : (Whh + (size_t)row * 512 + (kc - 64));
      h8 v;
#pragma unroll
      for (int j = 0; j < 8; ++j) v[j] = (_Float16)src[j];
      uint32_t off = ((uint32_t)(c * 1152 + kc * 2)) ^ (uint32_t)((c & 7) << 4);
      *(h8*)(lds + off) = v;
    }
    float bias0[8];
#pragma unroll
    for (int j = 0; j < 8; ++j) {
      int row = (j & 3) * 512 + hbase + ((j >> 2) << 4) + pp;
      bias0[j] = bih[row] + bhh[row];
    }
    __syncthreads();

    float cv0[2][4] = {{0.f,0.f,0.f,0.f},{0.f,0.f,0.f,0.f}};

    for (int t = 0; t < 256; ++t) {
      if (tid == 0) {
        if (t > 0) spin_ge(rdy + FIDX(0, t - 1), 16);
        if (t >= 15) spin_ge(dn + FIDX(0, t - 15), (t == 15) ? 16 : 42);
      }
      __builtin_amdgcn_s_barrier();         // control-only
      const __half* As = hbuf + (size_t)(t & 15) * 32768;
      h8 A0[8], A1[8];
#pragma unroll
      for (int i = 0; i < 8; ++i) A0[i] = gld16_sc1(As, i * 4096 + abb);
#pragma unroll
      for (int i = 0; i < 8; ++i) A1[i] = gld16_sc1(As, (8 + i) * 4096 + abb);
      f4 acc[8];
#pragma unroll
      for (int j = 0; j < 8; ++j) acc[j] = (f4){0.f, 0.f, 0.f, 0.f};
      // x part (kt 0,1) from L2-cached xt while recurrent loads fly
#pragma unroll
      for (int kt = 0; kt < 2; ++kt) {
        h8 a = *(const h8*)(xt + (size_t)t * 4096 + kt * 2048 + lg * 512
                            + (16 * wv + pp) * 8);
        KB0(kt, a);
      }
      WAITV(8);
#pragma unroll
      for (int i = 0; i < 8; ++i) KB0(2 + i, A0[i]);
      WAITV(0);
#pragma unroll
      for (int i = 0; i < 8; ++i) KB0(10 + i, A1[i]);
      // epilogue: thread owns h cols {hbase+pp, hbase+16+pp}, rows 16wv+4lg+r
      __half* Hd = hbuf + (size_t)((t + 1) & 15) * 32768;
      const int brow = 16 * wv + 4 * lg;
#pragma unroll
      for (int jh = 0; jh < 2; ++jh) {
        const int hg = hbase + jh * 16 + pp;
#pragma unroll
        for (int r = 0; r < 4; ++r) {
          float gi = sigm(acc[4*jh+0][r] + bias0[4*jh+0]);
          float gf = sigm(acc[4*jh+1][r] + bias0[4*jh+1]);
          float gg = tanh_f(acc[4*jh+2][r] + bias0[4*jh+2]);
          float go = sigm(acc[4*jh+3][r] + bias0[4*jh+3]);
          float cc = gf * cv0[jh][r] + gi * gg;
          cv0[jh][r] = cc;
          st_h_dc(Hd + (size_t)(hg >> 3) * 512 + (brow + r) * 8 + (hg & 7),
                  go * tanh_f(cc));
        }
      }
      __syncthreads();   // drains stores before flag add
      if (tid == 0) {
        __hip_atomic_fetch_add(rdy + FIDX(0, t), 1, __ATOMIC_RELAXED, __HIP_MEMORY_SCOPE_AGENT);
        __hip_atomic_fetch_add(dn  + FIDX(0, t), 1, __ATOMIC_RELAXED, __HIP_MEMORY_SCOPE_AGENT);
      }
    }
    return;
  }

  // ================= layers 1..9 =================
  const int cuIdx = role - 16;
  const int L = 1 + cuIdx / 26;
  const int cl = cuIdx % 26;
  const int S = cl < 18 ? 20 : 19;
  const int hbase = cl < 18 ? 20 * cl : 360 + 19 * (cl - 18);
  const float* WihL = Wih + (size_t)(L - 1) * 1048576;
  const float* WhhL = Whh + (size_t)L * 1048576;
  const float* bihL = bih + L * 2048;
  const float* bhhL = bhh + L * 2048;

  // weights kt 0..28 into LDS [80 cols][928 k], stride 1856B, XOR swizzle
  for (int ch = tid; ch < 9280; ch += 256) {
    int c = ch / 116, kc = (ch % 116) * 8;
    int row = colrow_main(c, S, hbase);
    const float* src = (kc < 512) ? (WihL + (size_t)row * 512 + kc)
                                  : (WhhL + (size_t)row * 512 + (kc - 512));
    h8 v;
#pragma unroll
    for (int j = 0; j < 8; ++j) v[j] = (_Float16)src[j];
    uint32_t off = ((uint32_t)(c * 1856 + kc * 2)) ^ (uint32_t)((c & 7) << 4);
    *(h8*)(lds + off) = v;
  }
  // streamed kt 29..31 fragments into LDS tail [148480, 163840)
  {
    const char* strmg = ws + STRM_OFF + (size_t)cuIdx * 15360;
    for (int ch = tid; ch < 960; ch += 256)
      *(h8*)(lds + 148480 + ch * 16) = *(const h8*)(strmg + ch * 16);
  }
  float biasv[4], bsp[4];
#pragma unroll
  for (int j = 0; j < 4; ++j) {
    int row = colrow_main(16 * j + pp, S, hbase);
    biasv[j] = bihL[row] + bhhL[row];
    int rs = colrow_main(64 + 4 * (pp >> 2) + j, S, hbase);
    bsp[j] = bihL[rs] + bhhL[rs];
  }
  __syncthreads();

  const int ncuP = (L == 1) ? 16 : 26;
  const int dnTgt = (L == 9) ? 32 : 52;
  const int pm = lane & 3;
  const int hj = 16 + (pp >> 2);

  float cv[4] = {0.f,0.f,0.f,0.f};
  float csp[4] = {0.f,0.f,0.f,0.f};

  for (int t = 0; t < 256; ++t) {
    if (tid == 0) spin_ge(rdy + FIDX(L - 1, t), ncuP);
    __builtin_amdgcn_s_barrier();           // control-only
    const __half* Abot = hbuf + ((size_t)(L - 1) * RSLOT + ((t + 1) & 15)) * 32768;
    const __half* Asel = hbuf + ((size_t)L * RSLOT + (t & 15)) * 32768;
    h8 A0[8], A1[8], A2[8], A3[8];
#pragma unroll
    for (int i = 0; i < 8; ++i) A0[i] = gld16_sc1(Abot, i * 4096 + abb);
#pragma unroll
    for (int i = 0; i < 8; ++i) A1[i] = gld16_sc1(Abot, (8 + i) * 4096 + abb);
    // hide sibling handoff under the Abot flight
    if (tid == 0) {
      if (t > 0) spin_ge(rdy + FIDX(L, t - 1), 26);
      if (t >= 15) spin_ge(dn + FIDX(L, t - 15), (t == 15) ? 26 : dnTgt);
    }
    __builtin_amdgcn_s_barrier();           // control-only
    f4 acc[5];
#pragma unroll
    for (int j = 0; j < 5; ++j) acc[j] = (f4){0.f, 0.f, 0.f, 0.f};
    WAITV(8);
#pragma unroll
    for (int i = 0; i < 8; ++i) KB(i, A0[i]);
#pragma unroll
    for (int i = 0; i < 8; ++i) A2[i] = gld16_sc1(Asel, i * 4096 + abb);
    WAITV(8);
#pragma unroll
    for (int i = 0; i < 8; ++i) KB(8 + i, A1[i]);
#pragma unroll
    for (int i = 0; i < 8; ++i) A3[i] = gld16_sc1(Asel, (8 + i) * 4096 + abb);
    WAITV(8);
#pragma unroll
    for (int i = 0; i < 8; ++i) KB(16 + i, A2[i]);
    WAITV(0);
#pragma unroll
    for (int i = 0; i < 8; ++i) KB(24 + i, A3[i]);

    // epilogue: thread owns h col hbase+pp (4 gates in-thread) + spare via 4-lane gather
    __half* Hd = hbuf + ((size_t)L * RSLOT + ((t + 1) & 15)) * 32768;
    const int brow = 16 * wv + 4 * lg;
    const int hgm = hbase + pp;
#pragma unroll
    for (int r = 0; r < 4; ++r) {
      float gi = sigm(acc[0][r] + biasv[0]);
      float gf = sigm(acc[1][r] + biasv[1]);
      float gg = tanh_f(acc[2][r] + biasv[2]);
      float go = sigm(acc[3][r] + biasv[3]);
      float cc = gf * cv[r] + gi * gg;
      cv[r] = cc;
      st_h_dc(Hd + (size_t)(hgm >> 3) * 512 + (brow + r) * 8 + (hgm & 7),
              go * tanh_f(cc));
      // spare col (c = 64+pp): gate = pm, h = 16+(pp>>2); gather 4 gates in 4-lane group
      float va = acc[4][r];
      float vb = __shfl_xor(va, 1);
      float vc = __shfl_xor(va, 2);
      float vd = __shfl_xor(vb, 2);
      float q0 = (pm & 2) ? ((pm & 1) ? vd : vc) : ((pm & 1) ? vb : va);
      float q1 = (pm & 2) ? ((pm & 1) ? vc : vd) : ((pm & 1) ? va : vb);
      float q2 = (pm & 2) ? ((pm & 1) ? vb : va) : ((pm & 1) ? vd : vc);
      float q3 = (pm & 2) ? ((pm & 1) ? va : vb) : ((pm & 1) ? vc : vd);
      float si = sigm(q0 + bsp[0]);
      float sf = sigm(q1 + bsp[1]);
      float sg = tanh_f(q2 + bsp[2]);
      float so = sigm(q3 + bsp[3]);
      float c3 = sf * csp[r] + si * sg;
      csp[r] = c3;
      if (pm == 0 && hj < S) {
        int hg = hbase + hj;
        st_h_dc(Hd + (size_t)(hg >> 3) * 512 + (brow + r) * 8 + (hg & 7),
                so * tanh_f(c3));
      }
    }

    __syncthreads();   // drains stores before flag adds
    if (tid == 0) {
      __hip_atomic_fetch_add(rdy + FIDX(L, t), 1, __ATOMIC_RELAXED, __HIP_MEMORY_SCOPE_AGENT);
      __hip_atomic_fetch_add(dn + FIDX(L - 1, t + 1), 1, __ATOMIC_RELAXED, __HIP_MEMORY_SCOPE_AGENT);
      __hip_atomic_fetch_add(dn + FIDX(L, t), 1, __ATOMIC_RELAXED, __HIP_MEMORY_SCOPE_AGENT);
    }
  }
}

// ---------------- host ----------------

extern "C" void kernel_launch(void* const* d_in, const int* in_sizes, int n_in,
                              void* d_out, int out_size, void* d_ws, size_t ws_size,
                              hipStream_t stream) {
  const float* X    = (const float*)d_in[0];
  const float* Wih0 = (const float*)d_in[1];
  const float* Wih  = (const float*)d_in[2];
  const float* Whh  = (const float*)d_in[3];
  const float* bihp = (const float*)d_in[4];
  const float* bhhp = (const float*)d_in[5];
  const float* Wout = (const float*)d_in[6];
  const float* bout = (const float*)d_in[7];
  float* out = (float*)d_out;
  char* ws = (char*)d_ws;
  (void)in_sizes; (void)n_in; (void)out_size;
  if (ws_size < WS_NEED) return;

  hipFuncSetAttribute((const void*)lstm_fused,
                      hipFuncAttributeMaxDynamicSharedMemorySize, 163840);

  zero_kernel<<<966, 256, 0, stream>>>(ws);
  xprep_kernel<<<512, 256, 0, stream>>>(X, ws);
  wsprep_kernel<<<878, 256, 0, stream>>>(Whh, ws);
  lstm_fused<<<256, 256, 163840, stream>>>(X, Wih0, Wih, Whh, bihp, bhhp,
                                           Wout, bout, out, ws);
}